// Round 1
// baseline (1206.433 us; speedup 1.0000x reference)
//
#include <hip/hip_runtime.h>
#include <hip/hip_bf16.h>

#define N_USERS 20000
#define N_ITEMS 30000
#define NTOT    50000
#define DIM     64
#define EXTRA_D 1152
#define E_EDGES 500000
#define NC      100

// ---------------- helpers ----------------
__device__ __forceinline__ float wred_sum(float v){
#pragma unroll
  for(int o=32;o;o>>=1) v += __shfl_xor(v,o,64);
  return v;
}
__device__ __forceinline__ int wred_sumi(int v){
#pragma unroll
  for(int o=32;o;o>>=1) v += __shfl_xor(v,o,64);
  return v;
}
__device__ __forceinline__ float wred_max(float v){
#pragma unroll
  for(int o=32;o;o>>=1) v = fmaxf(v,__shfl_xor(v,o,64));
  return v;
}
__device__ __forceinline__ float lrelu(float x){ return x>0.f? x : 0.2f*x; }
__device__ __forceinline__ unsigned fenc(float f){
  unsigned u=__float_as_uint(f); return (u&0x80000000u)? ~u : (u|0x80000000u);
}
__device__ __forceinline__ float fdec(unsigned k){
  return __uint_as_float((k&0x80000000u)? (k^0x80000000u) : ~k);
}

// ---------------- fusion MLP ----------------
// h[i,j] = relu( [item|extra][i,:] @ w1 + b1 ), i<30000, j<128, K=1216
__global__ __launch_bounds__(256) void fusion1_kernel(
    const float* __restrict__ item, const float* __restrict__ extra,
    const float* __restrict__ w1, const float* __restrict__ b1,
    float* __restrict__ h)
{
  __shared__ __align__(16) float As[16][68];   // transposed: As[k][m], stride 68 (272B, 16B-mult)
  __shared__ __align__(16) float Bs[16][128];
  const int tid = threadIdx.x;
  const int bm = blockIdx.x * 64;
  const int tx = tid & 31;        // cols tx*4..tx*4+3
  const int ty = tid >> 5;        // rows ty*8..ty*8+7
  const int lr = tid >> 2;        // A load row 0..63
  const int lc = (tid & 3) * 4;   // A load k 0,4,8,12
  const int brow = tid >> 4;      // B load row 0..15
  const int bcol = (tid & 15) * 8;
  float acc[8][4];
#pragma unroll
  for(int r=0;r<8;r++)
#pragma unroll
    for(int c=0;c<4;c++) acc[r][c]=0.f;
  const int gi = bm + lr;
  const bool rowok = gi < N_ITEMS;
  for(int k0=0;k0<DIM+EXTRA_D;k0+=16){
    float4 av = make_float4(0.f,0.f,0.f,0.f);
    if(rowok){
      int k = k0 + lc;
      if(k < DIM) av = *(const float4*)(item + (size_t)gi*DIM + k);
      else        av = *(const float4*)(extra + (size_t)gi*EXTRA_D + (k-DIM));
    }
    As[lc+0][lr]=av.x; As[lc+1][lr]=av.y; As[lc+2][lr]=av.z; As[lc+3][lr]=av.w;
    float4 bv0 = *(const float4*)(w1 + (size_t)(k0+brow)*128 + bcol);
    float4 bv1 = *(const float4*)(w1 + (size_t)(k0+brow)*128 + bcol + 4);
    *(float4*)&Bs[brow][bcol]   = bv0;
    *(float4*)&Bs[brow][bcol+4] = bv1;
    __syncthreads();
#pragma unroll
    for(int kk=0;kk<16;kk++){
      float4 a0 = *(const float4*)&As[kk][ty*8];
      float4 a1 = *(const float4*)&As[kk][ty*8+4];
      float4 b  = *(const float4*)&Bs[kk][tx*4];
      float a[8] = {a0.x,a0.y,a0.z,a0.w,a1.x,a1.y,a1.z,a1.w};
      float bb[4] = {b.x,b.y,b.z,b.w};
#pragma unroll
      for(int r=0;r<8;r++)
#pragma unroll
        for(int c=0;c<4;c++) acc[r][c] += a[r]*bb[c];
    }
    __syncthreads();
  }
  float4 bias = *(const float4*)(b1 + tx*4);
#pragma unroll
  for(int r=0;r<8;r++){
    int row = bm + ty*8 + r;
    if(row < N_ITEMS){
      float4 o;
      o.x = fmaxf(acc[r][0]+bias.x, 0.f);
      o.y = fmaxf(acc[r][1]+bias.y, 0.f);
      o.z = fmaxf(acc[r][2]+bias.z, 0.f);
      o.w = fmaxf(acc[r][3]+bias.w, 0.f);
      *(float4*)(h + (size_t)row*128 + tx*4) = o;
    }
  }
}

// X[20000+r,:] = h[r,:] @ w2 + b2
__global__ __launch_bounds__(256) void fusion2_kernel(
    const float* __restrict__ h, const float* __restrict__ w2, const float* __restrict__ b2,
    float* __restrict__ X)
{
  __shared__ __align__(16) float Wl[128*64];
  __shared__ float rowbuf[4][128];
  const int tid=threadIdx.x;
  for(int i=tid;i<128*64;i+=256) Wl[i]=w2[i];
  __syncthreads();
  const int lane = tid & 63, wv = tid>>6;
  const int nw = gridDim.x*4;
  const float b = b2[lane];
  for(int r = blockIdx.x*4+wv; r<N_ITEMS; r+=nw){
    rowbuf[wv][lane]      = h[(size_t)r*128+lane];
    rowbuf[wv][64+lane]   = h[(size_t)r*128+64+lane];
    float acc=0.f;
#pragma unroll 8
    for(int k=0;k<128;k++) acc += rowbuf[wv][k]*Wl[k*64+lane];
    X[(size_t)(N_USERS+r)*64+lane] = acc + b;
  }
}

__global__ void copy_user_kernel(const float* __restrict__ u, float* __restrict__ X){
  int i = blockIdx.x*256+threadIdx.x;
  int n4 = N_USERS*64/4;
  if(i<n4) ((float4*)X)[i] = ((const float4*)u)[i];
}

// ---------------- small reductions / coefs ----------------
__global__ void ea_sum_kernel(const float* __restrict__ ea, int n, float* __restrict__ out2){
  float a0=0.f,a1=0.f;
  for(int e=blockIdx.x*blockDim.x+threadIdx.x; e<n; e+=gridDim.x*blockDim.x){
    a0+=ea[2*e]; a1+=ea[2*e+1];
  }
  a0=wred_sum(a0); a1=wred_sum(a1);
  if((threadIdx.x&63)==0){ atomicAdd(&out2[0],a0); atomicAdd(&out2[1],a1); }
}

// coefs layout: [4]=mean_ea0 [5]=mean_ea1 [6]=mean_cea0 [7]=mean_cea1
//               [8+h]=cgA0[h] [12+h]=cgA1[h] (h<4)
//               [16+l*2+h]=A0[l][h] [20+l*2+h]=A1[l][h] (l<2,h<2)
__global__ void prep_small_kernel(const float* __restrict__ easum, int Ec,
    const float* __restrict__ cg_le, const float* __restrict__ cg_ae,
    const float* __restrict__ gat_le, const float* __restrict__ gat_ae,
    float* __restrict__ coefs)
{
  int tid=threadIdx.x; int lane=tid&63; int wv=tid>>6;
  {
    int hh=wv; // cluster heads 0..3
    float v0 = cg_le[hh*64+lane]*cg_ae[hh*64+lane];
    float v1 = cg_le[256 + hh*64+lane]*cg_ae[hh*64+lane];
    v0=wred_sum(v0); v1=wred_sum(v1);
    if(lane==0){ coefs[8+hh]=v0; coefs[12+hh]=v1; }
  }
  {
    int l=wv>>1, hh=wv&1;
    float v0 = gat_le[l*256 + hh*64+lane]     * gat_ae[l*128+hh*64+lane];
    float v1 = gat_le[l*256 + 128 + hh*64+lane]* gat_ae[l*128+hh*64+lane];
    v0=wred_sum(v0); v1=wred_sum(v1);
    if(lane==0){ coefs[16+l*2+hh]=v0; coefs[20+l*2+hh]=v1; }
  }
  if(tid==0){
    coefs[4]=easum[0]/(float)E_EDGES; coefs[5]=easum[1]/(float)E_EDGES;
    coefs[6]=easum[2]/(float)Ec;      coefs[7]=easum[3]/(float)Ec;
  }
}

// ---------------- CSR build (by dst) ----------------
__global__ void count_dst_kernel(const int* __restrict__ ei, int* __restrict__ cnt){
  int e = blockIdx.x*256+threadIdx.x;
  if(e<E_EDGES) atomicAdd(&cnt[ei[E_EDGES+e]],1);
}
__global__ __launch_bounds__(1024) void scan1_kernel(const int* __restrict__ cnt,
    int* __restrict__ incl, int* __restrict__ bsum){
  __shared__ int s[1024];
  int i = blockIdx.x*1024 + threadIdx.x;
  int v = (i<NTOT)? cnt[i]+1 : 0;
  s[threadIdx.x]=v; __syncthreads();
  for(int off=1; off<1024; off<<=1){
    int t = (threadIdx.x>=off)? s[threadIdx.x-off] : 0;
    __syncthreads();
    s[threadIdx.x]+=t;
    __syncthreads();
  }
  if(i<NTOT) incl[i]=s[threadIdx.x];
  if(threadIdx.x==1023) bsum[blockIdx.x]=s[1023];
}
__global__ void scan2_kernel(int* __restrict__ bsum, int nb){
  int lane=threadIdx.x;
  int v = (lane<nb)? bsum[lane]:0;
#pragma unroll
  for(int o=1;o<64;o<<=1){ int t=__shfl_up(v,o,64); if(lane>=o) v+=t; }
  if(lane<nb) bsum[lane]=v;
}
__global__ void scan3_kernel(const int* __restrict__ incl, const int* __restrict__ cnt,
    const int* __restrict__ bsum, int* __restrict__ offs, int* __restrict__ fillptr){
  int i=blockIdx.x*256+threadIdx.x;
  if(i<NTOT){
    int blk=i>>10;
    int prev = blk? bsum[blk-1]:0;
    int start = prev + incl[i] - (cnt[i]+1);
    offs[i]=start; fillptr[i]=start;
  }
  if(i==0) offs[NTOT]=E_EDGES+NTOT;
}
__global__ void fill_edges_kernel(const int* __restrict__ ei, const float* __restrict__ ea,
    int* __restrict__ fillptr, int* __restrict__ slot_src, float2* __restrict__ slot_ea){
  int e = blockIdx.x*256+threadIdx.x;
  if(e<E_EDGES){
    int dst=ei[E_EDGES+e], src=ei[e];
    int pos=atomicAdd(&fillptr[dst],1);
    slot_src[pos]=src;
    slot_ea[pos]=make_float2(ea[2*e],ea[2*e+1]);
  }
}
__global__ void fill_loops_kernel(int* __restrict__ fillptr, int* __restrict__ slot_src,
    float2* __restrict__ slot_ea, const float* __restrict__ coefs){
  int n = blockIdx.x*256+threadIdx.x;
  if(n<NTOT){
    int pos=atomicAdd(&fillptr[n],1);
    slot_src[pos]=n;
    slot_ea[pos]=make_float2(coefs[4],coefs[5]);
  }
}

// ---------------- GCN ----------------
__global__ void clflag_kernel(const int* __restrict__ ei, const int* __restrict__ ca, int* __restrict__ flag){
  int e = blockIdx.x*256+threadIdx.x;
  if(e<E_EDGES){
    int cs=ca[ei[e]];
    if(cs==ca[ei[E_EDGES+e]]) flag[cs]=1;
  }
}
__global__ void ccnt_kernel(const int* __restrict__ ca, int* __restrict__ ccnt){
  int n = blockIdx.x*256+threadIdx.x;
  if(n<NTOT) atomicAdd(&ccnt[ca[n]],1);
}
__global__ __launch_bounds__(256) void gcn_deg_kernel(const int* __restrict__ offs,
    const int* __restrict__ slot_src, const int* __restrict__ ca, float* __restrict__ dinv){
  int lane=threadIdx.x&63, wv=threadIdx.x>>6;
  int n = blockIdx.x*4+wv; if(n>=NTOT) return;
  int beg=offs[n], end=offs[n+1], myca=ca[n];
  int c=0;
  for(int j=beg+lane;j<end;j+=64) c += (ca[slot_src[j]]==myca)?1:0;
  c = wred_sumi(c);
  if(lane==0) dinv[n]=rsqrtf((float)c);
}
__global__ __launch_bounds__(256) void xw_kernel(const float* __restrict__ X,
    const float* __restrict__ gw, float* __restrict__ xw){
  __shared__ float Wl[64*64];
  __shared__ float rowb[4][64];
  int tid=threadIdx.x;
  for(int i=tid;i<4096;i+=256) Wl[i]=gw[i];
  __syncthreads();
  int lane=tid&63, wv=tid>>6;
  for(int r=blockIdx.x*4+wv; r<NTOT; r+=gridDim.x*4){
    rowb[wv][lane]=X[(size_t)r*64+lane];
    float acc=0.f;
#pragma unroll 8
    for(int k=0;k<64;k++) acc+=rowb[wv][k]*Wl[k*64+lane];
    xw[(size_t)r*64+lane]=acc;
  }
}
__global__ __launch_bounds__(256) void gcn_agg_kernel(const float* __restrict__ X,
    const float* __restrict__ xw, const float* __restrict__ gcn_b,
    const int* __restrict__ offs, const int* __restrict__ slot_src, const int* __restrict__ ca,
    const float* __restrict__ dinv, const int* __restrict__ flag,
    float* __restrict__ Xc, float* __restrict__ psum){
  int lane=threadIdx.x&63, wv=threadIdx.x>>6;
  int n=blockIdx.x*4+wv; if(n>=NTOT) return;
  int beg=offs[n], end=offs[n+1], myca=ca[n];
  float acc=0.f;
  for(int j=beg;j<end;j++){
    int s=slot_src[j];                       // wave-uniform broadcast
    if(ca[s]==myca) acc += dinv[s]*xw[(size_t)s*64+lane];
  }
  float gout = dinv[n]*acc + gcn_b[lane];
  float xc = flag[myca] ? gout : X[(size_t)n*64+lane];
  Xc[(size_t)n*64+lane]=xc;
  atomicAdd(&psum[myca*64+lane], xc);
}
__global__ void pooled_fin_kernel(const float* __restrict__ psum, const int* __restrict__ ccnt,
    float* __restrict__ pooled){
  int t = blockIdx.x*256+threadIdx.x;
  if(t<NC*64) pooled[t]=psum[t]/fmaxf((float)ccnt[t>>6],1.f);
}

// ---------------- cluster GAT ----------------
__global__ void xhc_kernel(const float* __restrict__ pooled, const float* __restrict__ cg_lin,
    float* __restrict__ xh_c){
  __shared__ float prow[64];
  int c=blockIdx.x, t=threadIdx.x;
  if(t<64) prow[t]=pooled[c*64+t];
  __syncthreads();
  float acc=0.f;
#pragma unroll 8
  for(int k=0;k<64;k++) acc += prow[k]*cg_lin[k*256+t];
  xh_c[c*256+t]=acc;
}
__global__ void attc_kernel(const float* __restrict__ xh_c, const float* __restrict__ as_,
    const float* __restrict__ ad_, float* __restrict__ asrc_c, float* __restrict__ adst_c){
  int c=blockIdx.x; int lane=threadIdx.x&63, hh=threadIdx.x>>6;
  float v=xh_c[c*256+hh*64+lane];
  float s=wred_sum(v*as_[hh*64+lane]);
  float d=wred_sum(v*ad_[hh*64+lane]);
  if(lane==0){ asrc_c[c*4+hh]=s; adst_c[c*4+hh]=d; }
}
__global__ __launch_bounds__(256) void cpass1_kernel(const int* __restrict__ cei,
    const float* __restrict__ cea, int Ec,
    const float* __restrict__ asrc_c, const float* __restrict__ adst_c,
    const float* __restrict__ coefs, unsigned* __restrict__ gmax){
  __shared__ unsigned lmax[NC*4];
  int t=threadIdx.x;
  for(int i=t;i<NC*4;i+=256) lmax[i]=0u;
  __syncthreads();
  int tot=Ec+NC;
  for(int i=blockIdx.x*256+t; i<tot; i+=gridDim.x*256){
    int s,d; float e0,e1;
    if(i<Ec){ s=cei[i]; d=cei[Ec+i]; e0=cea[2*i]; e1=cea[2*i+1]; }
    else    { s=d=i-Ec; e0=coefs[6]; e1=coefs[7]; }
#pragma unroll
    for(int hh=0;hh<4;hh++){
      float al = lrelu(asrc_c[s*4+hh]+adst_c[d*4+hh]+e0*coefs[8+hh]+e1*coefs[12+hh]);
      atomicMax(&lmax[d*4+hh], fenc(al));
    }
  }
  __syncthreads();
  for(int i=t;i<NC*4;i+=256) if(lmax[i]) atomicMax(&gmax[i], lmax[i]);
}
__global__ __launch_bounds__(256) void cpass2_kernel(const int* __restrict__ cei,
    const float* __restrict__ cea, int Ec,
    const float* __restrict__ asrc_c, const float* __restrict__ adst_c,
    const float* __restrict__ coefs, const unsigned* __restrict__ gmax, float* __restrict__ Wm){
  int t=threadIdx.x;
  int tot=Ec+NC;
  for(int i=blockIdx.x*256+t; i<tot; i+=gridDim.x*256){
    int s,d; float e0,e1;
    if(i<Ec){ s=cei[i]; d=cei[Ec+i]; e0=cea[2*i]; e1=cea[2*i+1]; }
    else    { s=d=i-Ec; e0=coefs[6]; e1=coefs[7]; }
#pragma unroll
    for(int hh=0;hh<4;hh++){
      float al = lrelu(asrc_c[s*4+hh]+adst_c[d*4+hh]+e0*coefs[8+hh]+e1*coefs[12+hh]);
      float ex = expf(al - fdec(gmax[d*4+hh]));
      atomicAdd(&Wm[(d*NC+s)*4+hh], ex);
    }
  }
}
__global__ __launch_bounds__(256) void clupd_kernel(const float* __restrict__ Wm,
    const float* __restrict__ xh_c, const float* __restrict__ cg_bias, float* __restrict__ cl_upd){
  __shared__ float shs[4];
  __shared__ float red[4][64];
  int c=blockIdx.x; int t=threadIdx.x; int lane=t&63, hh=t>>6;
  float p=0.f;
  if(lane<NC)    p += Wm[(c*NC+lane)*4+hh];
  if(lane+64<NC) p += Wm[(c*NC+lane+64)*4+hh];
  p=wred_sum(p);
  if(lane==0) shs[hh]=p+1e-16f;
  __syncthreads();
  float inv = 1.f/shs[hh];
  float acc=0.f;
  for(int s=0;s<NC;s++) acc += Wm[(c*NC+s)*4+hh]*xh_c[s*256+hh*64+lane];
  red[hh][lane]=acc*inv;
  __syncthreads();
  if(t<64) cl_upd[c*64+t]=0.25f*(red[0][t]+red[1][t]+red[2][t]+red[3][t])+cg_bias[t];
}
__global__ void xcomb_kernel(const float* __restrict__ Xc, const float* __restrict__ cl_upd,
    const int* __restrict__ ca, float* __restrict__ Xcomb){
  int idx = blockIdx.x*256+threadIdx.x;
  if(idx<NTOT*64){
    int n=idx>>6;
    Xcomb[idx]=Xc[idx]+cl_upd[ca[n]*64+(idx&63)];
  }
}

// ---------------- full-graph GAT layer ----------------
__global__ __launch_bounds__(256) void gat_xh_kernel(const float* __restrict__ Xin,
    const float* __restrict__ lin, const float* __restrict__ att_s, const float* __restrict__ att_d,
    float* __restrict__ xh, float* __restrict__ asrc, float* __restrict__ adst){
  __shared__ __align__(16) float Wl[64*128];
  __shared__ float rowb[4][64];
  int t=threadIdx.x;
  for(int i=t;i<8192;i+=256) Wl[i]=lin[i];
  __syncthreads();
  int lane=t&63, wv=t>>6;
  float as0=att_s[lane], as1=att_s[64+lane], ad0=att_d[lane], ad1=att_d[64+lane];
  for(int r=blockIdx.x*4+wv; r<NTOT; r+=gridDim.x*4){
    rowb[wv][lane]=Xin[(size_t)r*64+lane];
    float x0=0.f,x1=0.f;
#pragma unroll 8
    for(int k=0;k<64;k++){ float xv=rowb[wv][k]; x0+=xv*Wl[k*128+lane]; x1+=xv*Wl[k*128+64+lane]; }
    xh[(size_t)r*128+lane]=x0; xh[(size_t)r*128+64+lane]=x1;
    float p0=wred_sum(x0*as0);
    float p1=wred_sum(x1*as1);
    float q0=wred_sum(x0*ad0);
    float q1=wred_sum(x1*ad1);
    if(lane==0){ asrc[2*r]=p0; asrc[2*r+1]=p1; adst[2*r]=q0; adst[2*r+1]=q1; }
  }
}
__global__ __launch_bounds__(256) void gat_agg_kernel(const float* __restrict__ xh,
    const float* __restrict__ asrc, const float* __restrict__ adst,
    const int* __restrict__ offs, const int* __restrict__ slot_src, const float2* __restrict__ slot_ea,
    const float* __restrict__ coefs, int layer, const float* __restrict__ bias, float* __restrict__ g){
  int lane=threadIdx.x&63, wv=threadIdx.x>>6;
  int n=blockIdx.x*4+wv; if(n>=NTOT) return;
  float A00=coefs[16+layer*2+0], A01=coefs[16+layer*2+1];
  float A10=coefs[20+layer*2+0], A11=coefs[20+layer*2+1];
  int beg=offs[n], end=offs[n+1];
  float ad0=adst[2*n], ad1=adst[2*n+1];
  float m0=-1e30f,m1=-1e30f;
  for(int j=beg+lane;j<end;j+=64){
    int s=slot_src[j]; float2 e=slot_ea[j];
    float al0=lrelu(asrc[2*s]  +ad0+e.x*A00+e.y*A10);
    float al1=lrelu(asrc[2*s+1]+ad1+e.x*A01+e.y*A11);
    m0=fmaxf(m0,al0); m1=fmaxf(m1,al1);
  }
  m0=wred_max(m0); m1=wred_max(m1);
  float s0=0.f,s1=0.f;
  for(int j=beg+lane;j<end;j+=64){
    int s=slot_src[j]; float2 e=slot_ea[j];
    float al0=lrelu(asrc[2*s]  +ad0+e.x*A00+e.y*A10);
    float al1=lrelu(asrc[2*s+1]+ad1+e.x*A01+e.y*A11);
    s0+=expf(al0-m0); s1+=expf(al1-m1);
  }
  s0=wred_sum(s0); s1=wred_sum(s1);
  float inv0=1.f/(s0+1e-16f), inv1=1.f/(s1+1e-16f);
  float acc0=0.f,acc1=0.f;
  for(int j=beg;j<end;j++){
    int s=slot_src[j]; float2 e=slot_ea[j];        // wave-uniform broadcast
    float al0=lrelu(asrc[2*s]  +ad0+e.x*A00+e.y*A10);
    float al1=lrelu(asrc[2*s+1]+ad1+e.x*A01+e.y*A11);
    float w0=expf(al0-m0)*inv0, w1=expf(al1-m1)*inv1;
    acc0 += w0*xh[(size_t)s*128+lane];
    acc1 += w1*xh[(size_t)s*128+64+lane];
  }
  g[(size_t)n*64+lane]=0.5f*(acc0+acc1)+bias[lane];
}
__global__ __launch_bounds__(256) void stats_kernel(const float* __restrict__ g, float* __restrict__ stats){
  __shared__ float s1[64], s2[64];
  int t=threadIdx.x;
  if(t<64){s1[t]=0.f;s2[t]=0.f;}
  __syncthreads();
  float a=0.f,b=0.f;
  int stride=gridDim.x*256;
  for(int i=blockIdx.x*256+t;i<NTOT*64;i+=stride){ float v=g[i]; a+=v; b+=v*v; }
  atomicAdd(&s1[t&63],a); atomicAdd(&s2[t&63],b);
  __syncthreads();
  if(t<64){ atomicAdd(&stats[t],s1[t]); atomicAdd(&stats[64+t],s2[t]); }
}
__global__ void gnorm_elu_kernel(const float* __restrict__ g, const float* __restrict__ Xin,
    const float* __restrict__ stats, const float* __restrict__ gw, const float* __restrict__ gb,
    const float* __restrict__ gms, float* __restrict__ outp){
  const float invN = 1.f/(float)NTOT;
  int idx = blockIdx.x*256+threadIdx.x;
  if(idx<NTOT*64){
    int d=idx&63;
    float m=stats[d]*invN;
    float mm=gms[d]*m;
    float var=stats[64+d]*invN - 2.f*mm*m + mm*mm;
    float v=(g[idx]-mm)*rsqrtf(var+1e-5f)*gw[d]+gb[d];
    float z=v+Xin[idx];
    outp[idx]= z>0.f? z : expf(z)-1.f;
  }
}

// ---------------- launch ----------------
extern "C" void kernel_launch(void* const* d_in, const int* in_sizes, int n_in,
                              void* d_out, int out_size, void* d_ws, size_t ws_size,
                              hipStream_t stream)
{
  const float* extra = (const float*)d_in[0];
  const float* user  = (const float*)d_in[1];
  const float* item  = (const float*)d_in[2];
  const float* fw1 = (const float*)d_in[3];
  const float* fb1 = (const float*)d_in[4];
  const float* fw2 = (const float*)d_in[5];
  const float* fb2 = (const float*)d_in[6];
  const float* fea = (const float*)d_in[7];
  const float* gcn_w = (const float*)d_in[8];
  const float* gcn_b = (const float*)d_in[9];
  const float* cg_lin = (const float*)d_in[10];
  const float* cg_as = (const float*)d_in[11];
  const float* cg_ad = (const float*)d_in[12];
  const float* cg_le = (const float*)d_in[13];
  const float* cg_ae = (const float*)d_in[14];
  const float* cg_bias = (const float*)d_in[15];
  const float* cea = (const float*)d_in[16];
  const float* gat_lin = (const float*)d_in[17];
  const float* gat_as = (const float*)d_in[18];
  const float* gat_ad = (const float*)d_in[19];
  const float* gat_le = (const float*)d_in[20];
  const float* gat_ae = (const float*)d_in[21];
  const float* gat_bias = (const float*)d_in[22];
  const float* gn_w = (const float*)d_in[23];
  const float* gn_b = (const float*)d_in[24];
  const float* gn_ms = (const float*)d_in[25];
  const int* fei = (const int*)d_in[26];
  const int* ca  = (const int*)d_in[27];
  const int* cei = (const int*)d_in[28];
  const int Ec = in_sizes[16]/2;
  float* outp = (float*)d_out;

  char* w = (char*)d_ws;
  auto alloc=[&](size_t b)->char*{ char* p=w; w += (b+255)&~(size_t)255; return p; };

  // zero region (single memset)
  char* z0 = w;
  int* cnt_dst = (int*)alloc((size_t)NTOT*4);
  float* easum = (float*)alloc(16);
  int* clflag = (int*)alloc(NC*4);
  int* ccnt = (int*)alloc(NC*4);
  float* psum = (float*)alloc(NC*64*4);
  unsigned* gmax = (unsigned*)alloc(NC*4*4);
  float* Wm = (float*)alloc(NC*NC*4*4);
  float* stats0 = (float*)alloc(128*4);
  float* stats1 = (float*)alloc(128*4);
  size_t zbytes = (size_t)(w - z0);

  float* coefs = (float*)alloc(32*4);
  int* offs = (int*)alloc((size_t)(NTOT+1)*4);
  int* incl = (int*)alloc((size_t)NTOT*4);
  int* bsum = (int*)alloc(64*4);
  int* fillptr = (int*)alloc((size_t)NTOT*4);
  int* slot_src = (int*)alloc((size_t)(E_EDGES+NTOT)*4);
  float2* slot_ea = (float2*)alloc((size_t)(E_EDGES+NTOT)*8);
  float* dinv = (float*)alloc((size_t)NTOT*4);
  float* pooled = (float*)alloc(NC*64*4);
  float* xh_c = (float*)alloc(NC*256*4);
  float* asrc_c = (float*)alloc(NC*4*4);
  float* adst_c = (float*)alloc(NC*4*4);
  float* cl_upd = (float*)alloc(NC*64*4);
  float* asrc = (float*)alloc((size_t)NTOT*2*4);
  float* adst = (float*)alloc((size_t)NTOT*2*4);
  float* bufA = (float*)alloc((size_t)NTOT*64*4);   // X, then g
  float* bufB = (float*)alloc((size_t)NTOT*128*4);  // h, then Xc, then xh
  float* bufC = (float*)alloc((size_t)NTOT*64*4);   // xw, then Xcomb_b
  float* bufD = (float*)alloc((size_t)NTOT*64*4);   // Xcomb_a

  float* X  = bufA; float* g  = bufA;
  float* h  = bufB; float* Xc = bufB; float* xh = bufB;
  float* xw = bufC; float* Xb = bufC;
  float* Xa = bufD;

  hipMemsetAsync(z0, 0, zbytes, stream);

  copy_user_kernel<<<(N_USERS*16+255)/256,256,0,stream>>>(user, X);
  fusion1_kernel<<<(N_ITEMS+63)/64,256,0,stream>>>(item, extra, fw1, fb1, h);
  fusion2_kernel<<<512,256,0,stream>>>(h, fw2, fb2, X);

  ea_sum_kernel<<<512,256,0,stream>>>(fea, E_EDGES, easum);
  ea_sum_kernel<<<256,256,0,stream>>>(cea, Ec, easum+2);
  prep_small_kernel<<<1,256,0,stream>>>(easum, Ec, cg_le, cg_ae, gat_le, gat_ae, coefs);

  count_dst_kernel<<<(E_EDGES+255)/256,256,0,stream>>>(fei, cnt_dst);
  scan1_kernel<<<(NTOT+1023)/1024,1024,0,stream>>>(cnt_dst, incl, bsum);
  scan2_kernel<<<1,64,0,stream>>>(bsum, (NTOT+1023)/1024);
  scan3_kernel<<<(NTOT+255)/256,256,0,stream>>>(incl, cnt_dst, bsum, offs, fillptr);
  fill_edges_kernel<<<(E_EDGES+255)/256,256,0,stream>>>(fei, fea, fillptr, slot_src, slot_ea);
  fill_loops_kernel<<<(NTOT+255)/256,256,0,stream>>>(fillptr, slot_src, slot_ea, coefs);

  clflag_kernel<<<(E_EDGES+255)/256,256,0,stream>>>(fei, ca, clflag);
  ccnt_kernel<<<(NTOT+255)/256,256,0,stream>>>(ca, ccnt);
  gcn_deg_kernel<<<(NTOT+3)/4,256,0,stream>>>(offs, slot_src, ca, dinv);
  xw_kernel<<<1024,256,0,stream>>>(X, gcn_w, xw);
  gcn_agg_kernel<<<(NTOT+3)/4,256,0,stream>>>(X, xw, gcn_b, offs, slot_src, ca, dinv, clflag, Xc, psum);
  pooled_fin_kernel<<<(NC*64+255)/256,256,0,stream>>>(psum, ccnt, pooled);
  xhc_kernel<<<NC,256,0,stream>>>(pooled, cg_lin, xh_c);
  attc_kernel<<<NC,256,0,stream>>>(xh_c, cg_as, cg_ad, asrc_c, adst_c);
  cpass1_kernel<<<512,256,0,stream>>>(cei, cea, Ec, asrc_c, adst_c, coefs, gmax);
  cpass2_kernel<<<1024,256,0,stream>>>(cei, cea, Ec, asrc_c, adst_c, coefs, gmax, Wm);
  clupd_kernel<<<NC,256,0,stream>>>(Wm, xh_c, cg_bias, cl_upd);
  xcomb_kernel<<<(NTOT*64+255)/256,256,0,stream>>>(Xc, cl_upd, ca, Xa);

  // layer 0
  gat_xh_kernel<<<1024,256,0,stream>>>(Xa, gat_lin, gat_as, gat_ad, xh, asrc, adst);
  gat_agg_kernel<<<(NTOT+3)/4,256,0,stream>>>(xh, asrc, adst, offs, slot_src, slot_ea, coefs, 0, gat_bias, g);
  stats_kernel<<<256,256,0,stream>>>(g, stats0);
  gnorm_elu_kernel<<<(NTOT*64+255)/256,256,0,stream>>>(g, Xa, stats0, gn_w, gn_b, gn_ms, Xb);
  // layer 1
  gat_xh_kernel<<<1024,256,0,stream>>>(Xb, gat_lin+64*128, gat_as+128, gat_ad+128, xh, asrc, adst);
  gat_agg_kernel<<<(NTOT+3)/4,256,0,stream>>>(xh, asrc, adst, offs, slot_src, slot_ea, coefs, 1, gat_bias+64, g);
  stats_kernel<<<256,256,0,stream>>>(g, stats1);
  gnorm_elu_kernel<<<(NTOT*64+255)/256,256,0,stream>>>(g, Xb, stats1, gn_w+64, gn_b+64, gn_ms+64, outp);
}

// Round 3
// 1051.852 us; speedup vs baseline: 1.1470x; 1.1470x over previous
//
#include <hip/hip_runtime.h>
#include <hip/hip_bf16.h>

#define N_USERS 20000
#define N_ITEMS 30000
#define NTOT    50000
#define DIM     64
#define EXTRA_D 1152
#define E_EDGES 500000
#define NC      100
#define KTOT    1216
#define KSTEPS  38

typedef __attribute__((ext_vector_type(8))) short short8;
typedef __attribute__((ext_vector_type(4))) float v4f;

// ---------------- helpers ----------------
__device__ __forceinline__ float wred_sum(float v){
#pragma unroll
  for(int o=32;o;o>>=1) v += __shfl_xor(v,o,64);
  return v;
}
__device__ __forceinline__ int wred_sumi(int v){
#pragma unroll
  for(int o=32;o;o>>=1) v += __shfl_xor(v,o,64);
  return v;
}
__device__ __forceinline__ float wred_max(float v){
#pragma unroll
  for(int o=32;o;o>>=1) v = fmaxf(v,__shfl_xor(v,o,64));
  return v;
}
__device__ __forceinline__ float lrelu(float x){ return x>0.f? x : 0.2f*x; }
__device__ __forceinline__ unsigned fenc(float f){
  unsigned u=__float_as_uint(f); return (u&0x80000000u)? ~u : (u|0x80000000u);
}
__device__ __forceinline__ float fdec(unsigned k){
  return __uint_as_float((k&0x80000000u)? (k^0x80000000u) : ~k);
}
__device__ __forceinline__ short f2bf(float f){
  unsigned u=__float_as_uint(f);
  unsigned r=(u + 0x7FFFu + ((u>>16)&1u))>>16;
  return (short)r;
}

// ---------------- weight prep (fp32 -> bf16, tiled/transposed) ----------------
// w1t[s][n][kk] = bf16(w1[(s*32+kk)*128 + n]), s<38,n<128,kk<32
__global__ void prep_w1_kernel(const float* __restrict__ w1, short* __restrict__ w1t){
  int i = blockIdx.x*256+threadIdx.x;
  if(i < KSTEPS*128*32){
    int s = i>>12, rem = i&4095, n = rem>>5, kk = rem&31;
    w1t[i] = f2bf(w1[(s*32+kk)*128 + n]);
  }
}
// w2t[c][n] = bf16(w2[n*64+c]), c<64,n<128
__global__ void prep_w2_kernel(const float* __restrict__ w2, short* __restrict__ w2t){
  int i = blockIdx.x*256+threadIdx.x;
  if(i < 64*128){
    int c = i>>7, n = i&127;
    w2t[i] = f2bf(w2[n*64+c]);
  }
}

// ---------------- fused fusion MLP (MFMA bf16) ----------------
// per block: 128 item rows. h = relu([item|extra]@w1+b1) kept in LDS,
// X[N_USERS+row] = h@w2 + b2.
__global__ __launch_bounds__(256) void fusion_mfma_kernel(
    const float* __restrict__ item, const float* __restrict__ extra,
    const short* __restrict__ w1t, const float* __restrict__ b1,
    const short* __restrict__ w2t, const float* __restrict__ b2,
    float* __restrict__ X)
{
  __shared__ short As[128*40];
  __shared__ short Bs[128*40];
  __shared__ short Hs[128*136];   // h tile: 128 rows x 128 cols, stride 136 (16B-aligned, conflict-benign)
  const int tid = threadIdx.x;
  const int blk = blockIdx.x;
  const int w = tid>>6, lane = tid&63, quad = lane>>4, l16 = lane&15;
  const int mw = w&1, nw = w>>1;

  v4f acc[4][4];
#pragma unroll
  for(int a=0;a<4;a++)
#pragma unroll
    for(int b=0;b<4;b++) acc[a][b] = (v4f){0.f,0.f,0.f,0.f};

  const int arow = tid>>3;           // 0..31
  const int aoff = (tid&7)*4;        // 0,4,..28
  for(int s=0;s<KSTEPS;s++){
    const int k0 = s*32;
    // stage A: 128 rows x 32 k fp32 -> bf16
#pragma unroll
    for(int it=0;it<4;it++){
      int r = arow + it*32;
      int col = k0 + aoff;
      int gr = blk*128 + r; if(gr >= N_ITEMS) gr = N_ITEMS-1;
      float4 v = (col < DIM) ? *(const float4*)(item + (size_t)gr*DIM + col)
                             : *(const float4*)(extra + (size_t)gr*EXTRA_D + (col-DIM));
      short4 bv; bv.x=f2bf(v.x); bv.y=f2bf(v.y); bv.z=f2bf(v.z); bv.w=f2bf(v.w);
      *(short4*)&As[r*40 + aoff] = bv;
    }
    // stage B: coalesced copy from tiled bf16 image
#pragma unroll
    for(int it=0;it<2;it++){
      int idx = tid + it*256;
      int4 v = *(const int4*)(w1t + (size_t)s*4096 + idx*8);
      int n = idx>>2, kk = (idx&3)*8;
      *(int4*)&Bs[n*40 + kk] = v;
    }
    __syncthreads();
    short8 af[4], bf_[4];
#pragma unroll
    for(int i=0;i<4;i++){
      int m = mw*64 + i*16 + l16;
      af[i]  = *(const short8*)&As[m*40 + quad*8];
      int n = nw*64 + i*16 + l16;
      bf_[i] = *(const short8*)&Bs[n*40 + quad*8];
    }
#pragma unroll
    for(int mi=0;mi<4;mi++)
#pragma unroll
      for(int ni=0;ni<4;ni++)
        acc[mi][ni] = __builtin_amdgcn_mfma_f32_16x16x32_bf16(af[mi], bf_[ni], acc[mi][ni], 0,0,0);
    __syncthreads();
  }

  // h = relu(acc + b1) -> LDS (bf16)
#pragma unroll
  for(int ni=0;ni<4;ni++){
    int n = nw*64 + ni*16 + l16;
    float bias = b1[n];
#pragma unroll
    for(int mi=0;mi<4;mi++){
      int mbase = mw*64 + mi*16 + quad*4;
#pragma unroll
      for(int r=0;r<4;r++){
        float hv = fmaxf(acc[mi][ni][r] + bias, 0.f);
        Hs[(mbase+r)*136 + n] = f2bf(hv);
      }
    }
  }
  __syncthreads();

  // X_tile = h @ w2 + b2 ; wave w handles rows [w*32, w*32+32)
  v4f acc2[2][4];
#pragma unroll
  for(int a=0;a<2;a++)
#pragma unroll
    for(int b=0;b<4;b++) acc2[a][b] = (v4f){0.f,0.f,0.f,0.f};
#pragma unroll
  for(int ks=0;ks<4;ks++){
    short8 ha[2];
#pragma unroll
    for(int mi=0;mi<2;mi++){
      int m = w*32 + mi*16 + l16;
      ha[mi] = *(const short8*)&Hs[m*136 + ks*32 + quad*8];
    }
#pragma unroll
    for(int ni=0;ni<4;ni++){
      int c = ni*16 + l16;
      short8 wb = *(const short8*)(w2t + c*128 + ks*32 + quad*8);
#pragma unroll
      for(int mi=0;mi<2;mi++)
        acc2[mi][ni] = __builtin_amdgcn_mfma_f32_16x16x32_bf16(ha[mi], wb, acc2[mi][ni], 0,0,0);
    }
  }
#pragma unroll
  for(int ni=0;ni<4;ni++){
    int c = ni*16 + l16;
    float b2v = b2[c];
#pragma unroll
    for(int mi=0;mi<2;mi++){
      int mbase = w*32 + mi*16 + quad*4;
#pragma unroll
      for(int r=0;r<4;r++){
        int row = blk*128 + mbase + r;
        if(row < N_ITEMS) X[(size_t)(N_USERS+row)*64 + c] = acc2[mi][ni][r] + b2v;
      }
    }
  }
}

__global__ void copy_user_kernel(const float* __restrict__ u, float* __restrict__ X){
  int i = blockIdx.x*256+threadIdx.x;
  int n4 = N_USERS*64/4;
  if(i<n4) ((float4*)X)[i] = ((const float4*)u)[i];
}

// ---------------- small reductions / coefs ----------------
__global__ void ea_sum_kernel(const float* __restrict__ ea, int n, float* __restrict__ out2){
  float a0=0.f,a1=0.f;
  for(int e=blockIdx.x*blockDim.x+threadIdx.x; e<n; e+=gridDim.x*blockDim.x){
    a0+=ea[2*e]; a1+=ea[2*e+1];
  }
  a0=wred_sum(a0); a1=wred_sum(a1);
  if((threadIdx.x&63)==0){ atomicAdd(&out2[0],a0); atomicAdd(&out2[1],a1); }
}

// coefs layout: [4]=mean_ea0 [5]=mean_ea1 [6]=mean_cea0 [7]=mean_cea1
//               [8+h]=cgA0[h] [12+h]=cgA1[h] (h<4)
//               [16+l*2+h]=A0[l][h] [20+l*2+h]=A1[l][h] (l<2,h<2)
__global__ void prep_small_kernel(const float* __restrict__ easum, int Ec,
    const float* __restrict__ cg_le, const float* __restrict__ cg_ae,
    const float* __restrict__ gat_le, const float* __restrict__ gat_ae,
    float* __restrict__ coefs)
{
  int tid=threadIdx.x; int lane=tid&63; int wv=tid>>6;
  {
    int hh=wv; // cluster heads 0..3
    float v0 = cg_le[hh*64+lane]*cg_ae[hh*64+lane];
    float v1 = cg_le[256 + hh*64+lane]*cg_ae[hh*64+lane];
    v0=wred_sum(v0); v1=wred_sum(v1);
    if(lane==0){ coefs[8+hh]=v0; coefs[12+hh]=v1; }
  }
  {
    int l=wv>>1, hh=wv&1;
    float v0 = gat_le[l*256 + hh*64+lane]     * gat_ae[l*128+hh*64+lane];
    float v1 = gat_le[l*256 + 128 + hh*64+lane]* gat_ae[l*128+hh*64+lane];
    v0=wred_sum(v0); v1=wred_sum(v1);
    if(lane==0){ coefs[16+l*2+hh]=v0; coefs[20+l*2+hh]=v1; }
  }
  if(tid==0){
    coefs[4]=easum[0]/(float)E_EDGES; coefs[5]=easum[1]/(float)E_EDGES;
    coefs[6]=easum[2]/(float)Ec;      coefs[7]=easum[3]/(float)Ec;
  }
}

// ---------------- CSR build (by dst) ----------------
__global__ void count_dst_kernel(const int* __restrict__ ei, int* __restrict__ cnt){
  int e = blockIdx.x*256+threadIdx.x;
  if(e<E_EDGES) atomicAdd(&cnt[ei[E_EDGES+e]],1);
}
__global__ __launch_bounds__(1024) void scan1_kernel(const int* __restrict__ cnt,
    int* __restrict__ incl, int* __restrict__ bsum){
  __shared__ int s[1024];
  int i = blockIdx.x*1024 + threadIdx.x;
  int v = (i<NTOT)? cnt[i]+1 : 0;
  s[threadIdx.x]=v; __syncthreads();
  for(int off=1; off<1024; off<<=1){
    int t = (threadIdx.x>=off)? s[threadIdx.x-off] : 0;
    __syncthreads();
    s[threadIdx.x]+=t;
    __syncthreads();
  }
  if(i<NTOT) incl[i]=s[threadIdx.x];
  if(threadIdx.x==1023) bsum[blockIdx.x]=s[1023];
}
__global__ void scan2_kernel(int* __restrict__ bsum, int nb){
  int lane=threadIdx.x;
  int v = (lane<nb)? bsum[lane]:0;
#pragma unroll
  for(int o=1;o<64;o<<=1){ int t=__shfl_up(v,o,64); if(lane>=o) v+=t; }
  if(lane<nb) bsum[lane]=v;
}
__global__ void scan3_kernel(const int* __restrict__ incl, const int* __restrict__ cnt,
    const int* __restrict__ bsum, int* __restrict__ offs, int* __restrict__ fillptr){
  int i=blockIdx.x*256+threadIdx.x;
  if(i<NTOT){
    int blk=i>>10;
    int prev = blk? bsum[blk-1]:0;
    int start = prev + incl[i] - (cnt[i]+1);
    offs[i]=start; fillptr[i]=start;
  }
  if(i==0) offs[NTOT]=E_EDGES+NTOT;
}
__global__ void fill_edges_kernel(const int* __restrict__ ei, const float* __restrict__ ea,
    int* __restrict__ fillptr, int* __restrict__ slot_src, float2* __restrict__ slot_ea){
  int e = blockIdx.x*256+threadIdx.x;
  if(e<E_EDGES){
    int dst=ei[E_EDGES+e], src=ei[e];
    int pos=atomicAdd(&fillptr[dst],1);
    slot_src[pos]=src;
    slot_ea[pos]=make_float2(ea[2*e],ea[2*e+1]);
  }
}
__global__ void fill_loops_kernel(int* __restrict__ fillptr, int* __restrict__ slot_src,
    float2* __restrict__ slot_ea, const float* __restrict__ coefs){
  int n = blockIdx.x*256+threadIdx.x;
  if(n<NTOT){
    int pos=atomicAdd(&fillptr[n],1);
    slot_src[pos]=n;
    slot_ea[pos]=make_float2(coefs[4],coefs[5]);
  }
}

// ---------------- GCN ----------------
__global__ void clflag_kernel(const int* __restrict__ ei, const int* __restrict__ ca, int* __restrict__ flag){
  int e = blockIdx.x*256+threadIdx.x;
  if(e<E_EDGES){
    int cs=ca[ei[e]];
    if(cs==ca[ei[E_EDGES+e]]) flag[cs]=1;
  }
}
__global__ void ccnt_kernel(const int* __restrict__ ca, int* __restrict__ ccnt){
  int n = blockIdx.x*256+threadIdx.x;
  if(n<NTOT) atomicAdd(&ccnt[ca[n]],1);
}
__global__ __launch_bounds__(256) void gcn_deg_kernel(const int* __restrict__ offs,
    const int* __restrict__ slot_src, const int* __restrict__ ca, float* __restrict__ dinv){
  int lane=threadIdx.x&63, wv=threadIdx.x>>6;
  int n = blockIdx.x*4+wv; if(n>=NTOT) return;
  int beg=offs[n], end=offs[n+1], myca=ca[n];
  int c=0;
  for(int j=beg+lane;j<end;j+=64) c += (ca[slot_src[j]]==myca)?1:0;
  c = wred_sumi(c);
  if(lane==0) dinv[n]=rsqrtf((float)c);
}
__global__ __launch_bounds__(256) void xw_kernel(const float* __restrict__ X,
    const float* __restrict__ gw, float* __restrict__ xw){
  __shared__ float Wl[64*64];
  __shared__ float rowb[4][64];
  int tid=threadIdx.x;
  for(int i=tid;i<4096;i+=256) Wl[i]=gw[i];
  __syncthreads();
  int lane=tid&63, wv=tid>>6;
  for(int r=blockIdx.x*4+wv; r<NTOT; r+=gridDim.x*4){
    rowb[wv][lane]=X[(size_t)r*64+lane];
    float acc=0.f;
#pragma unroll 8
    for(int k=0;k<64;k++) acc+=rowb[wv][k]*Wl[k*64+lane];
    xw[(size_t)r*64+lane]=acc;
  }
}
__global__ __launch_bounds__(256) void gcn_agg_kernel(const float* __restrict__ X,
    const float* __restrict__ xw, const float* __restrict__ gcn_b,
    const int* __restrict__ offs, const int* __restrict__ slot_src, const int* __restrict__ ca,
    const float* __restrict__ dinv, const int* __restrict__ flag,
    float* __restrict__ Xc, float* __restrict__ psum){
  int lane=threadIdx.x&63, wv=threadIdx.x>>6;
  int n=blockIdx.x*4+wv; if(n>=NTOT) return;
  int beg=offs[n], end=offs[n+1], myca=ca[n];
  float acc=0.f;
  for(int j=beg;j<end;j++){
    int s=slot_src[j];                       // wave-uniform broadcast
    if(ca[s]==myca) acc += dinv[s]*xw[(size_t)s*64+lane];
  }
  float gout = dinv[n]*acc + gcn_b[lane];
  float xc = flag[myca] ? gout : X[(size_t)n*64+lane];
  Xc[(size_t)n*64+lane]=xc;
  atomicAdd(&psum[myca*64+lane], xc);
}
__global__ void pooled_fin_kernel(const float* __restrict__ psum, const int* __restrict__ ccnt,
    float* __restrict__ pooled){
  int t = blockIdx.x*256+threadIdx.x;
  if(t<NC*64) pooled[t]=psum[t]/fmaxf((float)ccnt[t>>6],1.f);
}

// ---------------- cluster GAT ----------------
__global__ void xhc_kernel(const float* __restrict__ pooled, const float* __restrict__ cg_lin,
    float* __restrict__ xh_c){
  __shared__ float prow[64];
  int c=blockIdx.x, t=threadIdx.x;
  if(t<64) prow[t]=pooled[c*64+t];
  __syncthreads();
  float acc=0.f;
#pragma unroll 8
  for(int k=0;k<64;k++) acc += prow[k]*cg_lin[k*256+t];
  xh_c[c*256+t]=acc;
}
__global__ void attc_kernel(const float* __restrict__ xh_c, const float* __restrict__ as_,
    const float* __restrict__ ad_, float* __restrict__ asrc_c, float* __restrict__ adst_c){
  int c=blockIdx.x; int lane=threadIdx.x&63, hh=threadIdx.x>>6;
  float v=xh_c[c*256+hh*64+lane];
  float s=wred_sum(v*as_[hh*64+lane]);
  float d=wred_sum(v*ad_[hh*64+lane]);
  if(lane==0){ asrc_c[c*4+hh]=s; adst_c[c*4+hh]=d; }
}
__global__ __launch_bounds__(256) void cpass1_kernel(const int* __restrict__ cei,
    const float* __restrict__ cea, int Ec,
    const float* __restrict__ asrc_c, const float* __restrict__ adst_c,
    const float* __restrict__ coefs, unsigned* __restrict__ gmax){
  __shared__ unsigned lmax[NC*4];
  int t=threadIdx.x;
  for(int i=t;i<NC*4;i+=256) lmax[i]=0u;
  __syncthreads();
  int tot=Ec+NC;
  for(int i=blockIdx.x*256+t; i<tot; i+=gridDim.x*256){
    int s,d; float e0,e1;
    if(i<Ec){ s=cei[i]; d=cei[Ec+i]; e0=cea[2*i]; e1=cea[2*i+1]; }
    else    { s=d=i-Ec; e0=coefs[6]; e1=coefs[7]; }
#pragma unroll
    for(int hh=0;hh<4;hh++){
      float al = lrelu(asrc_c[s*4+hh]+adst_c[d*4+hh]+e0*coefs[8+hh]+e1*coefs[12+hh]);
      atomicMax(&lmax[d*4+hh], fenc(al));
    }
  }
  __syncthreads();
  for(int i=t;i<NC*4;i+=256) if(lmax[i]) atomicMax(&gmax[i], lmax[i]);
}
__global__ __launch_bounds__(256) void cpass2_kernel(const int* __restrict__ cei,
    const float* __restrict__ cea, int Ec,
    const float* __restrict__ asrc_c, const float* __restrict__ adst_c,
    const float* __restrict__ coefs, const unsigned* __restrict__ gmax, float* __restrict__ Wm){
  int t=threadIdx.x;
  int tot=Ec+NC;
  for(int i=blockIdx.x*256+t; i<tot; i+=gridDim.x*256){
    int s,d; float e0,e1;
    if(i<Ec){ s=cei[i]; d=cei[Ec+i]; e0=cea[2*i]; e1=cea[2*i+1]; }
    else    { s=d=i-Ec; e0=coefs[6]; e1=coefs[7]; }
#pragma unroll
    for(int hh=0;hh<4;hh++){
      float al = lrelu(asrc_c[s*4+hh]+adst_c[d*4+hh]+e0*coefs[8+hh]+e1*coefs[12+hh]);
      float ex = expf(al - fdec(gmax[d*4+hh]));
      atomicAdd(&Wm[(d*NC+s)*4+hh], ex);
    }
  }
}
__global__ __launch_bounds__(256) void clupd_kernel(const float* __restrict__ Wm,
    const float* __restrict__ xh_c, const float* __restrict__ cg_bias, float* __restrict__ cl_upd){
  __shared__ float shs[4];
  __shared__ float red[4][64];
  int c=blockIdx.x; int t=threadIdx.x; int lane=t&63, hh=t>>6;
  float p=0.f;
  if(lane<NC)    p += Wm[(c*NC+lane)*4+hh];
  if(lane+64<NC) p += Wm[(c*NC+lane+64)*4+hh];
  p=wred_sum(p);
  if(lane==0) shs[hh]=p+1e-16f;
  __syncthreads();
  float inv = 1.f/shs[hh];
  float acc=0.f;
  for(int s=0;s<NC;s++) acc += Wm[(c*NC+s)*4+hh]*xh_c[s*256+hh*64+lane];
  red[hh][lane]=acc*inv;
  __syncthreads();
  if(t<64) cl_upd[c*64+t]=0.25f*(red[0][t]+red[1][t]+red[2][t]+red[3][t])+cg_bias[t];
}
__global__ void xcomb_kernel(const float* __restrict__ Xc, const float* __restrict__ cl_upd,
    const int* __restrict__ ca, float* __restrict__ Xcomb){
  int idx = blockIdx.x*256+threadIdx.x;
  if(idx<NTOT*64){
    int n=idx>>6;
    Xcomb[idx]=Xc[idx]+cl_upd[ca[n]*64+(idx&63)];
  }
}

// ---------------- full-graph GAT layer ----------------
__global__ __launch_bounds__(256) void gat_xh_kernel(const float* __restrict__ Xin,
    const float* __restrict__ lin, const float* __restrict__ att_s, const float* __restrict__ att_d,
    float* __restrict__ xh, float* __restrict__ asrc, float* __restrict__ adst){
  __shared__ __align__(16) float Wl[64*128];
  __shared__ float rowb[4][64];
  int t=threadIdx.x;
  for(int i=t;i<8192;i+=256) Wl[i]=lin[i];
  __syncthreads();
  int lane=t&63, wv=t>>6;
  float as0=att_s[lane], as1=att_s[64+lane], ad0=att_d[lane], ad1=att_d[64+lane];
  for(int r=blockIdx.x*4+wv; r<NTOT; r+=gridDim.x*4){
    rowb[wv][lane]=Xin[(size_t)r*64+lane];
    float x0=0.f,x1=0.f;
#pragma unroll 8
    for(int k=0;k<64;k++){ float xv=rowb[wv][k]; x0+=xv*Wl[k*128+lane]; x1+=xv*Wl[k*128+64+lane]; }
    xh[(size_t)r*128+lane]=x0; xh[(size_t)r*128+64+lane]=x1;
    float p0=wred_sum(x0*as0);
    float p1=wred_sum(x1*as1);
    float q0=wred_sum(x0*ad0);
    float q1=wred_sum(x1*ad1);
    if(lane==0){ asrc[2*r]=p0; asrc[2*r+1]=p1; adst[2*r]=q0; adst[2*r+1]=q1; }
  }
}
__global__ __launch_bounds__(256) void gat_agg_kernel(const float* __restrict__ xh,
    const float* __restrict__ asrc, const float* __restrict__ adst,
    const int* __restrict__ offs, const int* __restrict__ slot_src, const float2* __restrict__ slot_ea,
    const float* __restrict__ coefs, int layer, const float* __restrict__ bias, float* __restrict__ g){
  int lane=threadIdx.x&63, wv=threadIdx.x>>6;
  int n=blockIdx.x*4+wv; if(n>=NTOT) return;
  float A00=coefs[16+layer*2+0], A01=coefs[16+layer*2+1];
  float A10=coefs[20+layer*2+0], A11=coefs[20+layer*2+1];
  int beg=offs[n], end=offs[n+1];
  float ad0=adst[2*n], ad1=adst[2*n+1];
  float m0=-1e30f,m1=-1e30f;
  for(int j=beg+lane;j<end;j+=64){
    int s=slot_src[j]; float2 e=slot_ea[j];
    float al0=lrelu(asrc[2*s]  +ad0+e.x*A00+e.y*A10);
    float al1=lrelu(asrc[2*s+1]+ad1+e.x*A01+e.y*A11);
    m0=fmaxf(m0,al0); m1=fmaxf(m1,al1);
  }
  m0=wred_max(m0); m1=wred_max(m1);
  float s0=0.f,s1=0.f;
  for(int j=beg+lane;j<end;j+=64){
    int s=slot_src[j]; float2 e=slot_ea[j];
    float al0=lrelu(asrc[2*s]  +ad0+e.x*A00+e.y*A10);
    float al1=lrelu(asrc[2*s+1]+ad1+e.x*A01+e.y*A11);
    s0+=expf(al0-m0); s1+=expf(al1-m1);
  }
  s0=wred_sum(s0); s1=wred_sum(s1);
  float inv0=1.f/(s0+1e-16f), inv1=1.f/(s1+1e-16f);
  float acc0=0.f,acc1=0.f;
  for(int j=beg;j<end;j++){
    int s=slot_src[j]; float2 e=slot_ea[j];        // wave-uniform broadcast
    float al0=lrelu(asrc[2*s]  +ad0+e.x*A00+e.y*A10);
    float al1=lrelu(asrc[2*s+1]+ad1+e.x*A01+e.y*A11);
    float w0=expf(al0-m0)*inv0, w1=expf(al1-m1)*inv1;
    acc0 += w0*xh[(size_t)s*128+lane];
    acc1 += w1*xh[(size_t)s*128+64+lane];
  }
  g[(size_t)n*64+lane]=0.5f*(acc0+acc1)+bias[lane];
}
__global__ __launch_bounds__(256) void stats_kernel(const float* __restrict__ g, float* __restrict__ stats){
  __shared__ float s1[64], s2[64];
  int t=threadIdx.x;
  if(t<64){s1[t]=0.f;s2[t]=0.f;}
  __syncthreads();
  float a=0.f,b=0.f;
  int stride=gridDim.x*256;
  for(int i=blockIdx.x*256+t;i<NTOT*64;i+=stride){ float v=g[i]; a+=v; b+=v*v; }
  atomicAdd(&s1[t&63],a); atomicAdd(&s2[t&63],b);
  __syncthreads();
  if(t<64){ atomicAdd(&stats[t],s1[t]); atomicAdd(&stats[64+t],s2[t]); }
}
__global__ void gnorm_elu_kernel(const float* __restrict__ g, const float* __restrict__ Xin,
    const float* __restrict__ stats, const float* __restrict__ gw, const float* __restrict__ gb,
    const float* __restrict__ gms, float* __restrict__ outp){
  const float invN = 1.f/(float)NTOT;
  int idx = blockIdx.x*256+threadIdx.x;
  if(idx<NTOT*64){
    int d=idx&63;
    float m=stats[d]*invN;
    float mm=gms[d]*m;
    float var=stats[64+d]*invN - 2.f*mm*m + mm*mm;
    float v=(g[idx]-mm)*rsqrtf(var+1e-5f)*gw[d]+gb[d];
    float z=v+Xin[idx];
    outp[idx]= z>0.f? z : expf(z)-1.f;
  }
}

// ---------------- launch ----------------
extern "C" void kernel_launch(void* const* d_in, const int* in_sizes, int n_in,
                              void* d_out, int out_size, void* d_ws, size_t ws_size,
                              hipStream_t stream)
{
  const float* extra = (const float*)d_in[0];
  const float* user  = (const float*)d_in[1];
  const float* item  = (const float*)d_in[2];
  const float* fw1 = (const float*)d_in[3];
  const float* fb1 = (const float*)d_in[4];
  const float* fw2 = (const float*)d_in[5];
  const float* fb2 = (const float*)d_in[6];
  const float* fea = (const float*)d_in[7];
  const float* gcn_w = (const float*)d_in[8];
  const float* gcn_b = (const float*)d_in[9];
  const float* cg_lin = (const float*)d_in[10];
  const float* cg_as = (const float*)d_in[11];
  const float* cg_ad = (const float*)d_in[12];
  const float* cg_le = (const float*)d_in[13];
  const float* cg_ae = (const float*)d_in[14];
  const float* cg_bias = (const float*)d_in[15];
  const float* cea = (const float*)d_in[16];
  const float* gat_lin = (const float*)d_in[17];
  const float* gat_as = (const float*)d_in[18];
  const float* gat_ad = (const float*)d_in[19];
  const float* gat_le = (const float*)d_in[20];
  const float* gat_ae = (const float*)d_in[21];
  const float* gat_bias = (const float*)d_in[22];
  const float* gn_w = (const float*)d_in[23];
  const float* gn_b = (const float*)d_in[24];
  const float* gn_ms = (const float*)d_in[25];
  const int* fei = (const int*)d_in[26];
  const int* ca  = (const int*)d_in[27];
  const int* cei = (const int*)d_in[28];
  const int Ec = in_sizes[16]/2;
  float* outp = (float*)d_out;

  char* w = (char*)d_ws;
  auto alloc=[&](size_t b)->char*{ char* p=w; w += (b+255)&~(size_t)255; return p; };

  // zero region (single memset)
  char* z0 = w;
  int* cnt_dst = (int*)alloc((size_t)NTOT*4);
  float* easum = (float*)alloc(16);
  int* clflag = (int*)alloc(NC*4);
  int* ccnt = (int*)alloc(NC*4);
  float* psum = (float*)alloc(NC*64*4);
  unsigned* gmax = (unsigned*)alloc(NC*4*4);
  float* Wm = (float*)alloc(NC*NC*4*4);
  float* stats0 = (float*)alloc(128*4);
  float* stats1 = (float*)alloc(128*4);
  size_t zbytes = (size_t)(w - z0);

  float* coefs = (float*)alloc(32*4);
  int* offs = (int*)alloc((size_t)(NTOT+1)*4);
  int* incl = (int*)alloc((size_t)NTOT*4);
  int* bsum = (int*)alloc(64*4);
  int* fillptr = (int*)alloc((size_t)NTOT*4);
  int* slot_src = (int*)alloc((size_t)(E_EDGES+NTOT)*4);
  float2* slot_ea = (float2*)alloc((size_t)(E_EDGES+NTOT)*8);
  float* dinv = (float*)alloc((size_t)NTOT*4);
  float* pooled = (float*)alloc(NC*64*4);
  float* xh_c = (float*)alloc(NC*256*4);
  float* asrc_c = (float*)alloc(NC*4*4);
  float* adst_c = (float*)alloc(NC*4*4);
  float* cl_upd = (float*)alloc(NC*64*4);
  float* asrc = (float*)alloc((size_t)NTOT*2*4);
  float* adst = (float*)alloc((size_t)NTOT*2*4);
  short* w1t = (short*)alloc((size_t)KSTEPS*4096*2);
  short* w2t = (short*)alloc((size_t)64*128*2);
  float* bufA = (float*)alloc((size_t)NTOT*64*4);   // X, then g
  float* bufB = (float*)alloc((size_t)NTOT*128*4);  // Xc, then xh
  float* bufC = (float*)alloc((size_t)NTOT*64*4);   // xw, then Xcomb_b
  float* bufD = (float*)alloc((size_t)NTOT*64*4);   // Xcomb_a

  float* X  = bufA; float* g  = bufA;
  float* Xc = bufB; float* xh = bufB;
  float* xw = bufC; float* Xb = bufC;
  float* Xa = bufD;

  hipMemsetAsync(z0, 0, zbytes, stream);

  copy_user_kernel<<<(N_USERS*16+255)/256,256,0,stream>>>(user, X);
  prep_w1_kernel<<<(KSTEPS*4096+255)/256,256,0,stream>>>(fw1, w1t);
  prep_w2_kernel<<<(64*128+255)/256,256,0,stream>>>(fw2, w2t);
  fusion_mfma_kernel<<<(N_ITEMS+127)/128,256,0,stream>>>(item, extra, w1t, fb1, w2t, fb2, X);

  ea_sum_kernel<<<512,256,0,stream>>>(fea, E_EDGES, easum);
  ea_sum_kernel<<<256,256,0,stream>>>(cea, Ec, easum+2);
  prep_small_kernel<<<1,256,0,stream>>>(easum, Ec, cg_le, cg_ae, gat_le, gat_ae, coefs);

  count_dst_kernel<<<(E_EDGES+255)/256,256,0,stream>>>(fei, cnt_dst);
  scan1_kernel<<<(NTOT+1023)/1024,1024,0,stream>>>(cnt_dst, incl, bsum);
  scan2_kernel<<<1,64,0,stream>>>(bsum, (NTOT+1023)/1024);
  scan3_kernel<<<(NTOT+255)/256,256,0,stream>>>(incl, cnt_dst, bsum, offs, fillptr);
  fill_edges_kernel<<<(E_EDGES+255)/256,256,0,stream>>>(fei, fea, fillptr, slot_src, slot_ea);
  fill_loops_kernel<<<(NTOT+255)/256,256,0,stream>>>(fillptr, slot_src, slot_ea, coefs);

  clflag_kernel<<<(E_EDGES+255)/256,256,0,stream>>>(fei, ca, clflag);
  ccnt_kernel<<<(NTOT+255)/256,256,0,stream>>>(ca, ccnt);
  gcn_deg_kernel<<<(NTOT+3)/4,256,0,stream>>>(offs, slot_src, ca, dinv);
  xw_kernel<<<1024,256,0,stream>>>(X, gcn_w, xw);
  gcn_agg_kernel<<<(NTOT+3)/4,256,0,stream>>>(X, xw, gcn_b, offs, slot_src, ca, dinv, clflag, Xc, psum);
  pooled_fin_kernel<<<(NC*64+255)/256,256,0,stream>>>(psum, ccnt, pooled);
  xhc_kernel<<<NC,256,0,stream>>>(pooled, cg_lin, xh_c);
  attc_kernel<<<NC,256,0,stream>>>(xh_c, cg_as, cg_ad, asrc_c, adst_c);
  cpass1_kernel<<<512,256,0,stream>>>(cei, cea, Ec, asrc_c, adst_c, coefs, gmax);
  cpass2_kernel<<<1024,256,0,stream>>>(cei, cea, Ec, asrc_c, adst_c, coefs, gmax, Wm);
  clupd_kernel<<<NC,256,0,stream>>>(Wm, xh_c, cg_bias, cl_upd);
  xcomb_kernel<<<(NTOT*64+255)/256,256,0,stream>>>(Xc, cl_upd, ca, Xa);

  // layer 0
  gat_xh_kernel<<<1024,256,0,stream>>>(Xa, gat_lin, gat_as, gat_ad, xh, asrc, adst);
  gat_agg_kernel<<<(NTOT+3)/4,256,0,stream>>>(xh, asrc, adst, offs, slot_src, slot_ea, coefs, 0, gat_bias, g);
  stats_kernel<<<256,256,0,stream>>>(g, stats0);
  gnorm_elu_kernel<<<(NTOT*64+255)/256,256,0,stream>>>(g, Xa, stats0, gn_w, gn_b, gn_ms, Xb);
  // layer 1
  gat_xh_kernel<<<1024,256,0,stream>>>(Xb, gat_lin+64*128, gat_as+128, gat_ad+128, xh, asrc, adst);
  gat_agg_kernel<<<(NTOT+3)/4,256,0,stream>>>(xh, asrc, adst, offs, slot_src, slot_ea, coefs, 1, gat_bias+64, g);
  stats_kernel<<<256,256,0,stream>>>(g, stats1);
  gnorm_elu_kernel<<<(NTOT*64+255)/256,256,0,stream>>>(g, Xb, stats1, gn_w+64, gn_b+64, gn_ms+64, outp);
}